// Round 4
// baseline (119.808 us; speedup 1.0000x reference)
//
#include <hip/hip_runtime.h>

// Problem:
//   pos:    [1, 64, 1024]   float32
//   events: [2, 64, 131072] float32
//   out:    [2, 64, 131072] float32
// Semantics: out[b,e,t] = events[b,e,t-d_e] for t>=d_e else 0,
// where d_e = argmax(pos[0,e,:]) * (131072/1024).
//
// Single fused kernel (no d_ws — round-1 lesson: cross-kernel d_ws handoff
// consumed harness poison during timing). Each block recomputes its event's
// argmax locally (4 KB pos row, L2-resident), then streams its slice of the
// shifted copy with nontemporal loads/stores (134 MB touched exactly once).
// Floor: 134 MB / 6.5 TB/s ~= 21 us; harness poison fills (~83 us) dominate
// the reported dur_us.
//
// Round-3 lesson: __builtin_nontemporal_* requires native vector types, not
// HIP_vector_type structs -> use clang ext_vector_type(4).

typedef float fvec4 __attribute__((ext_vector_type(4)));

#define N_EVENTS 64
#define START_SIZE 1024
#define N_SAMPLES 131072
#define BATCH 2
#define FACTOR (N_SAMPLES / START_SIZE)      // 128
#define ROW_LEN4 (N_SAMPLES / 4)             // 32768 fvec4 per row
#define BLOCKS_PER_ROW 8
#define CHUNK4 (ROW_LEN4 / BLOCKS_PER_ROW)   // 4096 fvec4 per block
#define ITERS (CHUNK4 / 256)                 // 16 fvec4 per thread

__global__ __launch_bounds__(256) void dirac_fused_kernel(
        const fvec4* __restrict__ pos4,      // [64, 256] fvec4
        const fvec4* __restrict__ ev,        // [128, 32768] fvec4
        fvec4* __restrict__ out) {
    const int row   = blockIdx.x >> 3;       // 0..127  (b*64+e)
    const int chunk = blockIdx.x & (BLOCKS_PER_ROW - 1);
    const int e     = row & (N_EVENTS - 1);
    const int tid   = threadIdx.x;           // 0..255

    // ---- local argmax over pos[e][0..1023] (first-occurrence ties) ----
    fvec4 p = pos4[e * 256 + tid];
    float v = p.x; int bi = 4 * tid;
    if (p.y > v) { v = p.y; bi = 4 * tid + 1; }
    if (p.z > v) { v = p.z; bi = 4 * tid + 2; }
    if (p.w > v) { v = p.w; bi = 4 * tid + 3; }

    #pragma unroll
    for (int off = 32; off >= 1; off >>= 1) {
        float ov = __shfl_down(v, off, 64);
        int   oi = __shfl_down(bi, off, 64);
        if (ov > v || (ov == v && oi < bi)) { v = ov; bi = oi; }
    }

    __shared__ float sv[4];
    __shared__ int   si[4];
    if ((tid & 63) == 0) { sv[tid >> 6] = v; si[tid >> 6] = bi; }
    __syncthreads();

    float bv = sv[0]; int b = si[0];
    #pragma unroll
    for (int w = 1; w < 4; ++w) {
        if (sv[w] > bv || (sv[w] == bv && si[w] < b)) { bv = sv[w]; b = si[w]; }
    }
    const int d4 = b * (FACTOR / 4);         // fvec4-granular shift (mult of 32)

    // ---- shifted copy of this block's 4096-fvec4 contiguous chunk ----
    const int rowbase = row * ROW_LEN4;
    int t4 = chunk * CHUNK4 + tid;
    #pragma unroll
    for (int it = 0; it < ITERS; ++it, t4 += 256) {
        fvec4 val = (fvec4)(0.f, 0.f, 0.f, 0.f);
        if (t4 >= d4) {
            val = __builtin_nontemporal_load(&ev[rowbase + (t4 - d4)]);
        }
        __builtin_nontemporal_store(val, &out[rowbase + t4]);
    }
}

extern "C" void kernel_launch(void* const* d_in, const int* in_sizes, int n_in,
                              void* d_out, int out_size, void* d_ws, size_t ws_size,
                              hipStream_t stream) {
    const fvec4* pos4 = (const fvec4*)d_in[0];
    const fvec4* ev   = (const fvec4*)d_in[1];
    fvec4* out = (fvec4*)d_out;

    const int nblocks = BATCH * N_EVENTS * BLOCKS_PER_ROW;   // 1024
    dirac_fused_kernel<<<nblocks, 256, 0, stream>>>(pos4, ev, out);
}